// Round 11
// baseline (4817.777 us; speedup 1.0000x reference)
//
#include <hip/hip_runtime.h>

// 2-layer tanh RNN, B=64 T=512 H=512, f32 in/out.
// R11 = R10 pipeline UNCHANGED (blocks 0..63) + CLOCK BALLAST (blocks
// 64..255): 192 otherwise-idle CUs run dense independent-FMA chains until
// the real work publishes completion. Purpose: test/defeat DPM clock floor.
// Evidence: first dispatch of every bench = 45ms (10x steady) = clock ramp;
// steady state has 0.5% VALUBusy / 3% occupancy => governor has no reason
// to hold fmax; measured ~9us/step handoff = ~3-4k cycles only at ~500MHz.
// R10 history: deep rings + phase split + s_sleep backoff => no change vs R7
// (~9us/step) -- period is ONE recurrence handoff whose latency is clock-
// inflated, not protocol-stacked.

#define HD 512
#define BATCH 64
#define SEQ 512
#define NVOCAB 25
#define OUTD 1000
#define NWG 32
#define BH (BATCH * HD)
#define D1 8    // h1 ring depth
#define D2 4    // h2 ring depth
#define FPAD 16 // ints per flag slot (64 B line)
#define NBALLAST 192

typedef unsigned short u16;
typedef unsigned int u32;
typedef unsigned long long u64;
typedef __attribute__((ext_vector_type(8))) short short8;  // 8 bf16
typedef __attribute__((ext_vector_type(4))) float f32x4;

union FragU { u16 h[8]; u64 q[2]; short8 v; };

__device__ __forceinline__ float bf2f(u16 v) {
    union { u32 u; float f; } c; c.u = ((u32)v) << 16; return c.f;
}
__device__ __forceinline__ u16 f2bf(float f) {
    union { float f; u32 u; } c; c.f = f;
    return (u16)((c.u + 0x7FFFu + ((c.u >> 16) & 1u)) >> 16);  // RNE
}
__device__ __forceinline__ short8 ld_frag(const u16* p) {
    FragU f; u64* q = (u64*)p;
    f.q[0] = __hip_atomic_load(q + 0, __ATOMIC_RELAXED, __HIP_MEMORY_SCOPE_AGENT);
    f.q[1] = __hip_atomic_load(q + 1, __ATOMIC_RELAXED, __HIP_MEMORY_SCOPE_AGENT);
    return f.v;
}

// Zero header+rings; thread 1024 probes x's int width (int64 => odd words 0).
__global__ void init_kernel(u32* p, int n, const int* x32, int* flag) {
    int i = blockIdx.x * 256 + threadIdx.x;
    if (i == 1024) {
        int all0 = 1;
        for (int j = 0; j < 64; ++j) if (x32[2 * j + 1] != 0) all0 = 0;
        *flag = all0;
    } else if (i < n) p[i] = 0u;
}

// hdr (ints): flags0[32*FPAD] @0 | flags1[32*FPAD] @512 | is64 @1024 | junk @1500+
__global__ __launch_bounds__(256, 1) void rnn_fused(
    const float* __restrict__ Whh0, const float* __restrict__ Wih0,
    const int* __restrict__ x,
    const float* __restrict__ bih0, const float* __restrict__ bhh0,
    const float* __restrict__ Whh1, const float* __restrict__ Wih1,
    const float* __restrict__ bih1, const float* __restrict__ bhh1,
    u16* h1ring, u16* h2ring, float* h2final, int* hdr)
{
    int* flags0 = hdr;             // flags0[g*FPAD] == v <=> L0 WG g finished step v-1
    int* flags1 = hdr + NWG * FPAD;
    const int tid  = threadIdx.x;

    // ---------------- BALLAST: keep idle CUs busy -> hold high clocks ----------------
    if (blockIdx.x >= 2 * NWG) {
        int* watch = flags1 + (blockIdx.x & 31) * FPAD;
        float r0 = (float)(tid + 1) * 1e-3f, r1 = r0 + 0.1f, r2 = r0 + 0.2f,
              r3 = r0 + 0.3f, r4 = r0 + 0.4f, r5 = r0 + 0.5f,
              r6 = r0 + 0.6f, r7 = r0 + 0.7f;
        for (long it = 0; it < (1L << 22); ++it) {
            #pragma unroll 64
            for (int j = 0; j < 512; ++j) {
                r0 = __builtin_fmaf(r0, 1.0000001f, 1e-7f);
                r1 = __builtin_fmaf(r1, 0.9999999f, 1e-7f);
                r2 = __builtin_fmaf(r2, 1.0000002f, -1e-7f);
                r3 = __builtin_fmaf(r3, 0.9999998f, 1e-7f);
                r4 = __builtin_fmaf(r4, 1.0000001f, -1e-7f);
                r5 = __builtin_fmaf(r5, 0.9999999f, -1e-7f);
                r6 = __builtin_fmaf(r6, 1.0000002f, 1e-7f);
                r7 = __builtin_fmaf(r7, 0.9999998f, -1e-7f);
            }
            if (__hip_atomic_load(watch, __ATOMIC_RELAXED,
                                  __HIP_MEMORY_SCOPE_AGENT) >= SEQ) break;
        }
        float s = r0 + r1 + r2 + r3 + r4 + r5 + r6 + r7;
        if (s == 12345.678f) hdr[1500 + blockIdx.x] = tid;  // keep FMAs live
        return;
    }
    // ---------------------------------------------------------------------------------

    const int wave = tid >> 6;
    const int lane = tid & 63;
    const int quad = lane >> 4;
    const int l16  = lane & 15;
    const int layer = blockIdx.x >> 5;          // 0 or 1
    const int rowbase = (blockIdx.x & 31) * 16; // 32 WGs x 16 rows = 512
    const int arow = rowbase + l16;             // A row (m = lane&15)
    const int row0 = rowbase + quad * 4;        // C/D rows: quad*4 + reg
    const int col  = wave * 16 + l16;           // C/D col (batch)
    int* myflag = (layer ? flags1 : flags0) + (blockIdx.x & 31) * FPAD;

    __shared__ u16 ldsW[2][16][4][16][8];       // Wih1 hi/lo frags, 32 KB

    // Whh split hi/lo bf16, register-resident: A[m=lane&15][k=quad*8+j].
    const float* Wself = layer ? Whh1 : Whh0;
    short8 Ah[16], Al[16];
    #pragma unroll
    for (int kc = 0; kc < 16; ++kc) {
        FragU th, tl;
        #pragma unroll
        for (int j = 0; j < 8; ++j) {
            float w = Wself[arow * HD + kc * 32 + quad * 8 + j];
            u16 hi = f2bf(w);
            th.h[j] = hi;
            tl.h[j] = f2bf(w - bf2f(hi));
        }
        Ah[kc] = th.v; Al[kc] = tl.v;
    }
    if (layer && wave == 0) {  // all 4 waves share the same A rows
        #pragma unroll
        for (int kc = 0; kc < 16; ++kc) {
            FragU th, tl;
            #pragma unroll
            for (int j = 0; j < 8; ++j) {
                float w = Wih1[arow * HD + kc * 32 + quad * 8 + j];
                u16 hi = f2bf(w);
                th.h[j] = hi;
                tl.h[j] = f2bf(w - bf2f(hi));
            }
            *(short8*)&ldsW[0][kc][quad][l16][0] = th.v;
            *(short8*)&ldsW[1][kc][quad][l16][0] = tl.v;
        }
    }
    const float* bA = layer ? bih1 : bih0;
    const float* bB = layer ? bhh1 : bhh0;
    float bsum[4];
    #pragma unroll
    for (int i = 0; i < 4; ++i) bsum[i] = bA[row0 + i] + bB[row0 + i];
    const int is64 = hdr[1024];
    __syncthreads();

    if (layer == 0) {
        for (int t = 0; t < SEQ; ++t) {
            // x gather is h-independent: issue before the wait
            int xi = is64 ? (int)((const long long*)x)[col * SEQ + t]
                          : x[col * SEQ + t];
            float xw[4];
            #pragma unroll
            for (int i = 0; i < 4; ++i) xw[i] = Wih0[(row0 + i) * NVOCAB + xi];

            // wait: peers flags0 >= t (h1[t] done); WAR flags1 >= t-7
            if (wave == 0) {
                const int g = lane & 31;
                int* p = (lane < 32 ? flags0 : flags1) + g * FPAD;
                const int tgt = (lane < 32) ? t : (t - (D1 - 1));
                long guard = 0;
                while (true) {
                    int v = __hip_atomic_load(p, __ATOMIC_RELAXED,
                                              __HIP_MEMORY_SCOPE_AGENT);
                    if (__ballot(v < tgt) == 0ULL) break;
                    __builtin_amdgcn_s_sleep(1);
                    if (++guard > (1L << 21)) break;
                }
            }
            __syncthreads();

            const u16* hp = h1ring + (size_t)(t & (D1 - 1)) * BH + col * HD;
            short8 B2[16];
            #pragma unroll
            for (int kc = 0; kc < 16; ++kc)
                B2[kc] = ld_frag(hp + kc * 32 + quad * 8);
            f32x4 acc0 = {0.f,0.f,0.f,0.f}, acc1 = {0.f,0.f,0.f,0.f};
            #pragma unroll
            for (int kc = 0; kc < 16; ++kc) {
                acc0 = __builtin_amdgcn_mfma_f32_16x16x32_bf16(Ah[kc], B2[kc], acc0, 0, 0, 0);
                acc1 = __builtin_amdgcn_mfma_f32_16x16x32_bf16(Al[kc], B2[kc], acc1, 0, 0, 0);
            }
            u16 hv[4];
            #pragma unroll
            for (int i = 0; i < 4; ++i)
                hv[i] = f2bf(tanhf(acc0[i] + acc1[i] + bsum[i] + xw[i]));
            u64 pk = (u64)hv[0] | ((u64)hv[1] << 16) | ((u64)hv[2] << 32) | ((u64)hv[3] << 48);
            u64* dst = (u64*)(h1ring + (size_t)((t + 1) & (D1 - 1)) * BH + col * HD + row0);
            __hip_atomic_store(dst, pk, __ATOMIC_RELAXED, __HIP_MEMORY_SCOPE_AGENT);

            __syncthreads();  // drains vmcnt: h1[t+1] at coherent point
            if (tid == 0)
                __hip_atomic_store(myflag, t + 1, __ATOMIC_RELEASE,
                                   __HIP_MEMORY_SCOPE_AGENT);
        }
    } else {
        for (int t = 0; t < SEQ; ++t) {
            // ---- phase A: wait peers flags1 >= t (h2[t]) ----
            if (wave == 0) {
                const int g = lane & 31;
                int* p = flags1 + g * FPAD;
                long guard = 0;
                while (true) {
                    int v = __hip_atomic_load(p, __ATOMIC_RELAXED,
                                              __HIP_MEMORY_SCOPE_AGENT);
                    if (__ballot(v < t) == 0ULL) break;
                    __builtin_amdgcn_s_sleep(1);
                    if (++guard > (1L << 21)) break;
                }
            }
            __syncthreads();
            const u16* hp = h2ring + (size_t)(t & (D2 - 1)) * BH + col * HD;
            short8 B2[16];
            #pragma unroll
            for (int kc = 0; kc < 16; ++kc)
                B2[kc] = ld_frag(hp + kc * 32 + quad * 8);
            f32x4 acc0 = {0.f,0.f,0.f,0.f}, acc1 = {0.f,0.f,0.f,0.f};
            #pragma unroll
            for (int kc = 0; kc < 16; ++kc) {
                acc0 = __builtin_amdgcn_mfma_f32_16x16x32_bf16(Ah[kc], B2[kc], acc0, 0, 0, 0);
                acc1 = __builtin_amdgcn_mfma_f32_16x16x32_bf16(Al[kc], B2[kc], acc1, 0, 0, 0);
            }

            // ---- phase B: wait flags0 >= t+1 (h1[t+1]), then Wih1 MFMAs ----
            if (wave == 0) {
                const int g = lane & 31;
                int* p = flags0 + g * FPAD;
                const int tgt = t + 1;
                long guard = 0;
                while (true) {
                    int v = __hip_atomic_load(p, __ATOMIC_RELAXED,
                                              __HIP_MEMORY_SCOPE_AGENT);
                    if (__ballot(v < tgt) == 0ULL) break;
                    __builtin_amdgcn_s_sleep(1);
                    if (++guard > (1L << 21)) break;
                }
            }
            __syncthreads();
            const u16* hq = h1ring + (size_t)((t + 1) & (D1 - 1)) * BH + col * HD;
            short8 B1[16];
            #pragma unroll
            for (int kc = 0; kc < 16; ++kc)
                B1[kc] = ld_frag(hq + kc * 32 + quad * 8);
            #pragma unroll
            for (int kc = 0; kc < 16; ++kc) {
                short8 w1h = *(short8*)&ldsW[0][kc][quad][l16][0];
                short8 w1l = *(short8*)&ldsW[1][kc][quad][l16][0];
                acc0 = __builtin_amdgcn_mfma_f32_16x16x32_bf16(w1h, B1[kc], acc0, 0, 0, 0);
                acc1 = __builtin_amdgcn_mfma_f32_16x16x32_bf16(w1l, B1[kc], acc1, 0, 0, 0);
            }

            // ---- epilogue ----
            if (t < SEQ - 1) {
                u16 hv[4];
                #pragma unroll
                for (int i = 0; i < 4; ++i)
                    hv[i] = f2bf(tanhf(acc0[i] + acc1[i] + bsum[i]));
                u64 pk = (u64)hv[0] | ((u64)hv[1] << 16) | ((u64)hv[2] << 32) | ((u64)hv[3] << 48);
                u64* dst = (u64*)(h2ring + (size_t)((t + 1) & (D2 - 1)) * BH + col * HD + row0);
                __hip_atomic_store(dst, pk, __ATOMIC_RELAXED, __HIP_MEMORY_SCOPE_AGENT);
            } else {
                float hf[4];
                #pragma unroll
                for (int i = 0; i < 4; ++i)
                    hf[i] = tanhf(acc0[i] + acc1[i] + bsum[i]);
                *(f32x4*)(h2final + col * HD + row0) = *(f32x4*)hf;  // exact final h2
            }
            __syncthreads();  // drains vmcnt
            if (tid == 0)
                __hip_atomic_store(myflag, t + 1, __ATOMIC_RELEASE,
                                   __HIP_MEMORY_SCOPE_AGENT);
        }
    }
}

__global__ __launch_bounds__(256) void out_kernel(
    const float* __restrict__ h2last, const float* __restrict__ Wout,
    const float* __restrict__ bout, float* __restrict__ out)
{
    int o = blockIdx.x * 256 + threadIdx.x;
    int b = blockIdx.y;
    if (o >= OUTD) return;
    const float* hrow = h2last + b * HD;
    const float* wrow = Wout + o * HD;
    float acc = 0.f;
    for (int k = 0; k < HD; k += 4) {
        float4 hv = *(const float4*)(hrow + k);
        float4 wv = *(const float4*)(wrow + k);
        acc += hv.x * wv.x + hv.y * wv.y + hv.z * wv.z + hv.w * wv.w;
    }
    out[b * OUTD + o] = acc + bout[o];
}

extern "C" void kernel_launch(void* const* d_in, const int* in_sizes, int n_in,
                              void* d_out, int out_size, void* d_ws, size_t ws_size,
                              hipStream_t stream) {
    const int*   x     = (const int*)d_in[0];
    const float* W_ih0 = (const float*)d_in[1];
    const float* W_hh0 = (const float*)d_in[2];
    const float* b_ih0 = (const float*)d_in[3];
    const float* b_hh0 = (const float*)d_in[4];
    const float* W_ih1 = (const float*)d_in[5];
    const float* W_hh1 = (const float*)d_in[6];
    const float* b_ih1 = (const float*)d_in[7];
    const float* b_hh1 = (const float*)d_in[8];
    const float* W_out = (const float*)d_in[9];
    const float* b_out = (const float*)d_in[10];

    // ws: hdr[2048] int | h1ring u16[D1][BH] (512K) | h2ring u16[D2][BH] (256K)
    //     | h2final f32[BH] (128K)  => 904 KB total
    const size_t needed = 8192 + (size_t)D1 * BH * 2 + (size_t)D2 * BH * 2
                        + (size_t)BH * 4;
    if (ws_size < needed) return;  // signature: absmax=0.149 non-NaN => ws short

    int* hdr = (int*)d_ws;
    u16* h1ring = (u16*)((char*)d_ws + 8192);
    u16* h2ring = h1ring + (size_t)D1 * BH;
    float* h2final = (float*)(h2ring + (size_t)D2 * BH);

    const int nzero = (int)((8192 + (size_t)(D1 + D2) * BH * 2) / 4);
    init_kernel<<<(nzero + 255) / 256, 256, 0, stream>>>((u32*)d_ws, nzero, x, hdr + 1024);
    rnn_fused<<<2 * NWG + NBALLAST, 256, 0, stream>>>(W_hh0, W_ih0, x, b_ih0, b_hh0,
                                                      W_hh1, W_ih1, b_ih1, b_hh1,
                                                      h1ring, h2ring, h2final, hdr);
    out_kernel<<<dim3(4, BATCH), 256, 0, stream>>>(h2final, W_out, b_out, (float*)d_out);
}

// Round 12
// 4807.681 us; speedup vs baseline: 1.0021x; 1.0021x over previous
//
#include <hip/hip_runtime.h>

// 2-layer tanh RNN, B=64 T=512 H=512, f32 in/out.
// R12 = R10/R11 RNN pipeline UNCHANGED (blocks 0..63) + MEMORY ballast
// (blocks 64..255): throttled agent-scope (cache-bypass) load stream from a
// 1MB MALL-resident region, ~0.5-1 TB/s aggregate. Purpose: hold the DATA
// FABRIC / MALL clock at high DPM. Evidence: R11 FMA ballast raised VALUBusy
// to 69% with ZERO effect on the 8.9us handoff => CU clocks not the limiter;
// every measured sync cost is ~integer multiples of a ~2us coherent-point RT
// (4-5x the cycle-model RT) => fabric clock floor is the prime suspect; this
// kernel's own traffic (70 GB/s = 1% util) cannot lift DF DPM.

#define HD 512
#define BATCH 64
#define SEQ 512
#define NVOCAB 25
#define OUTD 1000
#define NWG 32
#define BH (BATCH * HD)
#define D1 8    // h1 ring depth
#define D2 4    // h2 ring depth
#define FPAD 16 // ints per flag slot (64 B line)
#define NBALLAST 192

typedef unsigned short u16;
typedef unsigned int u32;
typedef unsigned long long u64;
typedef __attribute__((ext_vector_type(8))) short short8;  // 8 bf16
typedef __attribute__((ext_vector_type(4))) float f32x4;

union FragU { u16 h[8]; u64 q[2]; short8 v; };

__device__ __forceinline__ float bf2f(u16 v) {
    union { u32 u; float f; } c; c.u = ((u32)v) << 16; return c.f;
}
__device__ __forceinline__ u16 f2bf(float f) {
    union { float f; u32 u; } c; c.f = f;
    return (u16)((c.u + 0x7FFFu + ((c.u >> 16) & 1u)) >> 16);  // RNE
}
__device__ __forceinline__ short8 ld_frag(const u16* p) {
    FragU f; u64* q = (u64*)p;
    f.q[0] = __hip_atomic_load(q + 0, __ATOMIC_RELAXED, __HIP_MEMORY_SCOPE_AGENT);
    f.q[1] = __hip_atomic_load(q + 1, __ATOMIC_RELAXED, __HIP_MEMORY_SCOPE_AGENT);
    return f.v;
}

// Zero header+rings; thread 1024 probes x's int width (int64 => odd words 0).
__global__ void init_kernel(u32* p, int n, const int* x32, int* flag) {
    int i = blockIdx.x * 256 + threadIdx.x;
    if (i == 1024) {
        int all0 = 1;
        for (int j = 0; j < 64; ++j) if (x32[2 * j + 1] != 0) all0 = 0;
        *flag = all0;
    } else if (i < n) p[i] = 0u;
}

// hdr (ints): flags0[32*FPAD] @0 | flags1[32*FPAD] @512 | is64 @1024 | junk @1500+
__global__ __launch_bounds__(256, 1) void rnn_fused(
    const float* __restrict__ Whh0, const float* __restrict__ Wih0,
    const int* __restrict__ x,
    const float* __restrict__ bih0, const float* __restrict__ bhh0,
    const float* __restrict__ Whh1, const float* __restrict__ Wih1,
    const float* __restrict__ bih1, const float* __restrict__ bhh1,
    u16* h1ring, u16* h2ring, float* h2final, int* hdr)
{
    int* flags0 = hdr;             // flags0[g*FPAD] == v <=> L0 WG g finished step v-1
    int* flags1 = hdr + NWG * FPAD;
    const int tid  = threadIdx.x;

    // -------- MEMORY BALLAST: keep Data Fabric / MALL clocks high --------
    // Agent-scope loads bypass L1/L2 -> guaranteed XCD->IF->MALL traffic.
    // Throttled by s_sleep to ~0.5-1 TB/s aggregate across 192 WGs.
    if (blockIdx.x >= 2 * NWG) {
        int* watch = flags1 + (blockIdx.x & 31) * FPAD;
        const u64* src = (const u64*)Whh0;   // 512*512 f32 = 131072 u64 (1 MB)
        u64 acc = 0;
        for (long it = 0; it < (1L << 22); ++it) {
            int base = (int)(((u32)it * 2654435761u + (u32)blockIdx.x * 8191u) & 131071u);
            #pragma unroll
            for (int j = 0; j < 8; ++j) {
                int idx = (base + j * 16384 + tid * 2) & 131071;
                acc ^= __hip_atomic_load(src + idx, __ATOMIC_RELAXED,
                                         __HIP_MEMORY_SCOPE_AGENT);
            }
            __builtin_amdgcn_s_sleep(64);
            __builtin_amdgcn_s_sleep(64);
            if (__hip_atomic_load(watch, __ATOMIC_RELAXED,
                                  __HIP_MEMORY_SCOPE_AGENT) >= SEQ) break;
        }
        if (acc == 0xDEADBEEFULL) hdr[1500 + blockIdx.x] = tid;  // keep loads live
        return;
    }
    // ---------------------------------------------------------------------

    const int wave = tid >> 6;
    const int lane = tid & 63;
    const int quad = lane >> 4;
    const int l16  = lane & 15;
    const int layer = blockIdx.x >> 5;          // 0 or 1
    const int rowbase = (blockIdx.x & 31) * 16; // 32 WGs x 16 rows = 512
    const int arow = rowbase + l16;             // A row (m = lane&15)
    const int row0 = rowbase + quad * 4;        // C/D rows: quad*4 + reg
    const int col  = wave * 16 + l16;           // C/D col (batch)
    int* myflag = (layer ? flags1 : flags0) + (blockIdx.x & 31) * FPAD;

    __shared__ u16 ldsW[2][16][4][16][8];       // Wih1 hi/lo frags, 32 KB

    // Whh split hi/lo bf16, register-resident: A[m=lane&15][k=quad*8+j].
    const float* Wself = layer ? Whh1 : Whh0;
    short8 Ah[16], Al[16];
    #pragma unroll
    for (int kc = 0; kc < 16; ++kc) {
        FragU th, tl;
        #pragma unroll
        for (int j = 0; j < 8; ++j) {
            float w = Wself[arow * HD + kc * 32 + quad * 8 + j];
            u16 hi = f2bf(w);
            th.h[j] = hi;
            tl.h[j] = f2bf(w - bf2f(hi));
        }
        Ah[kc] = th.v; Al[kc] = tl.v;
    }
    if (layer && wave == 0) {  // all 4 waves share the same A rows
        #pragma unroll
        for (int kc = 0; kc < 16; ++kc) {
            FragU th, tl;
            #pragma unroll
            for (int j = 0; j < 8; ++j) {
                float w = Wih1[arow * HD + kc * 32 + quad * 8 + j];
                u16 hi = f2bf(w);
                th.h[j] = hi;
                tl.h[j] = f2bf(w - bf2f(hi));
            }
            *(short8*)&ldsW[0][kc][quad][l16][0] = th.v;
            *(short8*)&ldsW[1][kc][quad][l16][0] = tl.v;
        }
    }
    const float* bA = layer ? bih1 : bih0;
    const float* bB = layer ? bhh1 : bhh0;
    float bsum[4];
    #pragma unroll
    for (int i = 0; i < 4; ++i) bsum[i] = bA[row0 + i] + bB[row0 + i];
    const int is64 = hdr[1024];
    __syncthreads();

    if (layer == 0) {
        for (int t = 0; t < SEQ; ++t) {
            // x gather is h-independent: issue before the wait
            int xi = is64 ? (int)((const long long*)x)[col * SEQ + t]
                          : x[col * SEQ + t];
            float xw[4];
            #pragma unroll
            for (int i = 0; i < 4; ++i) xw[i] = Wih0[(row0 + i) * NVOCAB + xi];

            // wait: peers flags0 >= t (h1[t] done); WAR flags1 >= t-7
            if (wave == 0) {
                const int g = lane & 31;
                int* p = (lane < 32 ? flags0 : flags1) + g * FPAD;
                const int tgt = (lane < 32) ? t : (t - (D1 - 1));
                long guard = 0;
                while (true) {
                    int v = __hip_atomic_load(p, __ATOMIC_RELAXED,
                                              __HIP_MEMORY_SCOPE_AGENT);
                    if (__ballot(v < tgt) == 0ULL) break;
                    __builtin_amdgcn_s_sleep(1);
                    if (++guard > (1L << 21)) break;
                }
            }
            __syncthreads();

            const u16* hp = h1ring + (size_t)(t & (D1 - 1)) * BH + col * HD;
            short8 B2[16];
            #pragma unroll
            for (int kc = 0; kc < 16; ++kc)
                B2[kc] = ld_frag(hp + kc * 32 + quad * 8);
            f32x4 acc0 = {0.f,0.f,0.f,0.f}, acc1 = {0.f,0.f,0.f,0.f};
            #pragma unroll
            for (int kc = 0; kc < 16; ++kc) {
                acc0 = __builtin_amdgcn_mfma_f32_16x16x32_bf16(Ah[kc], B2[kc], acc0, 0, 0, 0);
                acc1 = __builtin_amdgcn_mfma_f32_16x16x32_bf16(Al[kc], B2[kc], acc1, 0, 0, 0);
            }
            u16 hv[4];
            #pragma unroll
            for (int i = 0; i < 4; ++i)
                hv[i] = f2bf(tanhf(acc0[i] + acc1[i] + bsum[i] + xw[i]));
            u64 pk = (u64)hv[0] | ((u64)hv[1] << 16) | ((u64)hv[2] << 32) | ((u64)hv[3] << 48);
            u64* dst = (u64*)(h1ring + (size_t)((t + 1) & (D1 - 1)) * BH + col * HD + row0);
            __hip_atomic_store(dst, pk, __ATOMIC_RELAXED, __HIP_MEMORY_SCOPE_AGENT);

            __syncthreads();  // drains vmcnt: h1[t+1] at coherent point
            if (tid == 0)
                __hip_atomic_store(myflag, t + 1, __ATOMIC_RELEASE,
                                   __HIP_MEMORY_SCOPE_AGENT);
        }
    } else {
        for (int t = 0; t < SEQ; ++t) {
            // ---- phase A: wait peers flags1 >= t (h2[t]) ----
            if (wave == 0) {
                const int g = lane & 31;
                int* p = flags1 + g * FPAD;
                long guard = 0;
                while (true) {
                    int v = __hip_atomic_load(p, __ATOMIC_RELAXED,
                                              __HIP_MEMORY_SCOPE_AGENT);
                    if (__ballot(v < t) == 0ULL) break;
                    __builtin_amdgcn_s_sleep(1);
                    if (++guard > (1L << 21)) break;
                }
            }
            __syncthreads();
            const u16* hp = h2ring + (size_t)(t & (D2 - 1)) * BH + col * HD;
            short8 B2[16];
            #pragma unroll
            for (int kc = 0; kc < 16; ++kc)
                B2[kc] = ld_frag(hp + kc * 32 + quad * 8);
            f32x4 acc0 = {0.f,0.f,0.f,0.f}, acc1 = {0.f,0.f,0.f,0.f};
            #pragma unroll
            for (int kc = 0; kc < 16; ++kc) {
                acc0 = __builtin_amdgcn_mfma_f32_16x16x32_bf16(Ah[kc], B2[kc], acc0, 0, 0, 0);
                acc1 = __builtin_amdgcn_mfma_f32_16x16x32_bf16(Al[kc], B2[kc], acc1, 0, 0, 0);
            }

            // ---- phase B: wait flags0 >= t+1 (h1[t+1]), then Wih1 MFMAs ----
            if (wave == 0) {
                const int g = lane & 31;
                int* p = flags0 + g * FPAD;
                const int tgt = t + 1;
                long guard = 0;
                while (true) {
                    int v = __hip_atomic_load(p, __ATOMIC_RELAXED,
                                              __HIP_MEMORY_SCOPE_AGENT);
                    if (__ballot(v < tgt) == 0ULL) break;
                    __builtin_amdgcn_s_sleep(1);
                    if (++guard > (1L << 21)) break;
                }
            }
            __syncthreads();
            const u16* hq = h1ring + (size_t)((t + 1) & (D1 - 1)) * BH + col * HD;
            short8 B1[16];
            #pragma unroll
            for (int kc = 0; kc < 16; ++kc)
                B1[kc] = ld_frag(hq + kc * 32 + quad * 8);
            #pragma unroll
            for (int kc = 0; kc < 16; ++kc) {
                short8 w1h = *(short8*)&ldsW[0][kc][quad][l16][0];
                short8 w1l = *(short8*)&ldsW[1][kc][quad][l16][0];
                acc0 = __builtin_amdgcn_mfma_f32_16x16x32_bf16(w1h, B1[kc], acc0, 0, 0, 0);
                acc1 = __builtin_amdgcn_mfma_f32_16x16x32_bf16(w1l, B1[kc], acc1, 0, 0, 0);
            }

            // ---- epilogue ----
            if (t < SEQ - 1) {
                u16 hv[4];
                #pragma unroll
                for (int i = 0; i < 4; ++i)
                    hv[i] = f2bf(tanhf(acc0[i] + acc1[i] + bsum[i]));
                u64 pk = (u64)hv[0] | ((u64)hv[1] << 16) | ((u64)hv[2] << 32) | ((u64)hv[3] << 48);
                u64* dst = (u64*)(h2ring + (size_t)((t + 1) & (D2 - 1)) * BH + col * HD + row0);
                __hip_atomic_store(dst, pk, __ATOMIC_RELAXED, __HIP_MEMORY_SCOPE_AGENT);
            } else {
                float hf[4];
                #pragma unroll
                for (int i = 0; i < 4; ++i)
                    hf[i] = tanhf(acc0[i] + acc1[i] + bsum[i]);
                *(f32x4*)(h2final + col * HD + row0) = *(f32x4*)hf;  // exact final h2
            }
            __syncthreads();  // drains vmcnt
            if (tid == 0)
                __hip_atomic_store(myflag, t + 1, __ATOMIC_RELEASE,
                                   __HIP_MEMORY_SCOPE_AGENT);
        }
    }
}

__global__ __launch_bounds__(256) void out_kernel(
    const float* __restrict__ h2last, const float* __restrict__ Wout,
    const float* __restrict__ bout, float* __restrict__ out)
{
    int o = blockIdx.x * 256 + threadIdx.x;
    int b = blockIdx.y;
    if (o >= OUTD) return;
    const float* hrow = h2last + b * HD;
    const float* wrow = Wout + o * HD;
    float acc = 0.f;
    for (int k = 0; k < HD; k += 4) {
        float4 hv = *(const float4*)(hrow + k);
        float4 wv = *(const float4*)(wrow + k);
        acc += hv.x * wv.x + hv.y * wv.y + hv.z * wv.z + hv.w * wv.w;
    }
    out[b * OUTD + o] = acc + bout[o];
}

extern "C" void kernel_launch(void* const* d_in, const int* in_sizes, int n_in,
                              void* d_out, int out_size, void* d_ws, size_t ws_size,
                              hipStream_t stream) {
    const int*   x     = (const int*)d_in[0];
    const float* W_ih0 = (const float*)d_in[1];
    const float* W_hh0 = (const float*)d_in[2];
    const float* b_ih0 = (const float*)d_in[3];
    const float* b_hh0 = (const float*)d_in[4];
    const float* W_ih1 = (const float*)d_in[5];
    const float* W_hh1 = (const float*)d_in[6];
    const float* b_ih1 = (const float*)d_in[7];
    const float* b_hh1 = (const float*)d_in[8];
    const float* W_out = (const float*)d_in[9];
    const float* b_out = (const float*)d_in[10];

    // ws: hdr[2048] int | h1ring u16[D1][BH] (512K) | h2ring u16[D2][BH] (256K)
    //     | h2final f32[BH] (128K)  => 904 KB total
    const size_t needed = 8192 + (size_t)D1 * BH * 2 + (size_t)D2 * BH * 2
                        + (size_t)BH * 4;
    if (ws_size < needed) return;  // signature: absmax=0.149 non-NaN => ws short

    int* hdr = (int*)d_ws;
    u16* h1ring = (u16*)((char*)d_ws + 8192);
    u16* h2ring = h1ring + (size_t)D1 * BH;
    float* h2final = (float*)(h2ring + (size_t)D2 * BH);

    const int nzero = (int)((8192 + (size_t)(D1 + D2) * BH * 2) / 4);
    init_kernel<<<(nzero + 255) / 256, 256, 0, stream>>>((u32*)d_ws, nzero, x, hdr + 1024);
    rnn_fused<<<2 * NWG + NBALLAST, 256, 0, stream>>>(W_hh0, W_ih0, x, b_ih0, b_hh0,
                                                      W_hh1, W_ih1, b_ih1, b_hh1,
                                                      h1ring, h2ring, h2final, hdr);
    out_kernel<<<dim3(4, BATCH), 256, 0, stream>>>(h2final, W_out, b_out, (float*)d_out);
}